// Round 3
// baseline (1561.660 us; speedup 1.0000x reference)
//
#include <hip/hip_runtime.h>
#include <hip/hip_bf16.h>
#include <cmath>
#include <cfloat>

#define BATCH 4
#define NPTS 8192
#define NPOINT 409
#define NBALLS (BATCH * NPOINT)   // 1636
#define REP_NS 20
#define REP_BLOCKS 128

// ws layout (bytes):
//   [0, 6544)      : fps_idx  int[1636]
//   [8192, 9216)   : rep_part double[128]   (per-block sums of the 4 rep terms)
//   [10240, 23328) : uni_part double[1636]  (per-ball weighted sums)
#define WS_FPS_OFF 0
#define WS_REP_OFF 8192
#define WS_UNI_OFF 10240

struct UniParams {
  float  thr[5];   // round-nearest f32 of (sqrt(p))^2 in double
  float  e[5];     // expect_len (f32)
  float  eden[5];  // expect_len + 1e-8 (f32)
  int    ns[5];
  int    off[5];   // prefix offsets into member list (sum = 407)
};

// ---------------------------------------------------------------- FPS
// One block per batch, 512 threads x 16 points in registers.
// Exact f32 arithmetic (no FMA contraction) to match the reference's
// sequential argmax chain; tie-break = first occurrence (smaller index).
__global__ __launch_bounds__(512) void fps_kernel(const float* __restrict__ pcd,
                                                  int* __restrict__ fps_idx) {
  const int b = blockIdx.x;
  const int t = threadIdx.x;
  const float* P = pcd + b * NPTS * 3;

  float px[16], py[16], pz[16], dist[16];
  const int base = t * 16;
#pragma unroll
  for (int k = 0; k < 16; k++) {
    px[k] = P[(base + k) * 3 + 0];
    py[k] = P[(base + k) * 3 + 1];
    pz[k] = P[(base + k) * 3 + 2];
    dist[k] = 1e10f;
  }

  __shared__ float sv[8];
  __shared__ int   si[8];
  __shared__ int   s_far;

  int far = 0;
  for (int s = 0; s < NPOINT; s++) {
    if (t == 0) fps_idx[b * NPOINT + s] = far;
    const float fx = P[far * 3 + 0];
    const float fy = P[far * 3 + 1];
    const float fz = P[far * 3 + 2];

    float best = -1.0f;
    int bidx = 0;
#pragma unroll
    for (int k = 0; k < 16; k++) {
      const float dx = __fsub_rn(px[k], fx);
      const float dy = __fsub_rn(py[k], fy);
      const float dz = __fsub_rn(pz[k], fz);
      const float d = __fadd_rn(__fadd_rn(__fmul_rn(dx, dx), __fmul_rn(dy, dy)),
                                __fmul_rn(dz, dz));
      const float nd = fminf(dist[k], d);
      dist[k] = nd;
      if (nd > best) { best = nd; bidx = base + k; }   // ascending k: first occurrence
    }
    // 64-lane wave reduce; lane order == index order, ties -> smaller index
#pragma unroll
    for (int off = 32; off >= 1; off >>= 1) {
      const float ov = __shfl_down(best, off);
      const int   oi = __shfl_down(bidx, off);
      if (ov > best) { best = ov; bidx = oi; }
      else if (ov == best && oi < bidx) { bidx = oi; }
    }
    const int lane = t & 63, wv = t >> 6;
    if (lane == 0) { sv[wv] = best; si[wv] = bidx; }
    __syncthreads();
    if (t == 0) {
      for (int w2 = 1; w2 < 8; w2++) {
        if (sv[w2] > best) { best = sv[w2]; bidx = si[w2]; }
        else if (sv[w2] == best && si[w2] < bidx) { bidx = si[w2]; }
      }
      s_far = bidx;
    }
    __syncthreads();
    far = s_far;
  }
}

// ---------------------------------------------------------------- repulsion
__device__ __forceinline__ void ins5(float v, float& t0, float& t1, float& t2,
                                     float& t3, float& t4) {
  if (v < t4) {
    t4 = v;
    if (t4 < t3) { float tmp = t3; t3 = t4; t4 = tmp; }
    if (t3 < t2) { float tmp = t2; t2 = t3; t3 = tmp; }
    if (t2 < t1) { float tmp = t1; t1 = t2; t2 = tmp; }
    if (t1 < t0) { float tmp = t0; t0 = t1; t1 = tmp; }
  }
}

__device__ __forceinline__ float rep_term(float d) {
  d = fmaxf(d, 0.0f);
  return 0.07f - sqrtf(d) * expf(-(d / 0.0009f));
}

// thread-per-query; LDS-tiled scan over the batch's 8192 points in index
// order (== ballquery sorted-key order). Online top-5-smallest multiset,
// first-20-hits cap, pad with first hit's distance (self-hit => cnt>=1).
__global__ __launch_bounds__(256) void rep_kernel(const float* __restrict__ pcd,
                                                  double* __restrict__ rep_part,
                                                  float thr) {
  __shared__ float sx[256], sy[256], sz[256];
  __shared__ float rbuf[4];
  const int tid = threadIdx.x;
  const int b = blockIdx.x >> 5;                       // 32 blocks per batch
  const int i = ((blockIdx.x & 31) << 8) + tid;
  const float* P = pcd + b * NPTS * 3;
  const float qx = P[i * 3 + 0], qy = P[i * 3 + 1], qz = P[i * 3 + 2];

  int cnt = 0;
  float d0 = 0.0f;
  float t0 = FLT_MAX, t1 = FLT_MAX, t2 = FLT_MAX, t3 = FLT_MAX, t4 = FLT_MAX;

  for (int tile = 0; tile < NPTS; tile += 256) {
    const int j = tile + tid;
    sx[tid] = P[j * 3 + 0];
    sy[tid] = P[j * 3 + 1];
    sz[tid] = P[j * 3 + 2];
    __syncthreads();
#pragma unroll 4
    for (int jj = 0; jj < 256; jj++) {
      const float dx = qx - sx[jj];
      const float dy = qy - sy[jj];
      const float dz = qz - sz[jj];
      const float d = dx * dx + dy * dy + dz * dz;
      if (d <= thr && cnt < REP_NS) {
        if (cnt == 0) d0 = d;
        ins5(d, t0, t1, t2, t3, t4);
        cnt++;
      }
    }
    __syncthreads();
  }
  for (int c = cnt; c < REP_NS; c++) ins5(d0, t0, t1, t2, t3, t4);

  // drop the single smallest (t0), keep 2nd..5th smallest
  float sum = rep_term(t1) + rep_term(t2) + rep_term(t3) + rep_term(t4);
#pragma unroll
  for (int off = 32; off >= 1; off >>= 1) sum += __shfl_down(sum, off);
  const int lane = tid & 63, wv = tid >> 6;
  if (lane == 0) rbuf[wv] = sum;
  __syncthreads();
  if (tid == 0) {
    rep_part[blockIdx.x] = (double)rbuf[0] + (double)rbuf[1] +
                           (double)rbuf[2] + (double)rbuf[3];
  }
}

// ---------------------------------------------------------------- uniform
// block-per-ball; ordered compaction of first-ns hits (index order) into
// per-percentage LDS member lists, pad with member 0, then per-row
// second-smallest pairwise distance. Per-ball weighted sum -> uni_part.
__global__ __launch_bounds__(256) void uni_kernel(const float* __restrict__ pcd,
                                                  const int* __restrict__ fps_idx,
                                                  double* __restrict__ uni_part,
                                                  UniParams up) {
  const int ball = blockIdx.x;
  const int b = ball / NPOINT;
  const int tid = threadIdx.x;
  const int lane = tid & 63, wv = tid >> 6;
  const float* P = pcd + b * NPTS * 3;

  const int qidx = fps_idx[ball];
  const float qx = P[qidx * 3 + 0], qy = P[qidx * 3 + 1], qz = P[qidx * 3 + 2];

  __shared__ float lst[407 * 3];
  __shared__ int s_cnt[5];
  __shared__ int wtot[4][5];
  __shared__ double dpart[4];

  if (tid < 5) s_cnt[tid] = 0;
  __syncthreads();

  for (int tile = 0; tile < NPTS; tile += 256) {
    const int j = tile + tid;
    const float x = P[j * 3 + 0];
    const float y = P[j * 3 + 1];
    const float z = P[j * 3 + 2];
    const float dx = qx - x, dy = qy - y, dz = qz - z;
    const float d = dx * dx + dy * dy + dz * dz;

    int hit[5], pre[5];
#pragma unroll
    for (int jp = 0; jp < 5; jp++) {
      const bool h = (d <= up.thr[jp]);
      const unsigned long long m = __ballot(h);
      pre[jp] = __popcll(m & ((1ull << lane) - 1ull));
      if (lane == 0) wtot[wv][jp] = __popcll(m);
      hit[jp] = h ? 1 : 0;
    }
    __syncthreads();
#pragma unroll
    for (int jp = 0; jp < 5; jp++) {
      if (hit[jp]) {
        int woff = 0;
        for (int w2 = 0; w2 < wv; w2++) woff += wtot[w2][jp];
        const int pos = s_cnt[jp] + woff + pre[jp];
        if (pos < up.ns[jp]) {
          float* L = &lst[(up.off[jp] + pos) * 3];
          L[0] = x; L[1] = y; L[2] = z;
        }
      }
    }
    __syncthreads();
    if (tid < 5) {
      s_cnt[tid] += wtot[0][tid] + wtot[1][tid] + wtot[2][tid] + wtot[3][tid];
    }
    __syncthreads();
  }

  // pad each list with its first member (self-hit guarantees >=1 member)
#pragma unroll
  for (int jp = 0; jp < 5; jp++) {
    const int c = min(s_cnt[jp], up.ns[jp]);
    const float m0x = lst[up.off[jp] * 3 + 0];
    const float m0y = lst[up.off[jp] * 3 + 1];
    const float m0z = lst[up.off[jp] * 3 + 2];
    for (int pos = c + tid; pos < up.ns[jp]; pos += 256) {
      float* L = &lst[(up.off[jp] + pos) * 3];
      L[0] = m0x; L[1] = m0y; L[2] = m0z;
    }
  }
  __syncthreads();

  // rows 0..406: second-smallest pairwise sqdist within the row's list
  double local = 0.0;
  for (int r = tid; r < 407; r += 256) {
    const int jp = (r < 32) ? 0 : (r < 97) ? 1 : (r < 178) ? 2 : (r < 276) ? 3 : 4;
    const int ri = r - up.off[jp];
    const int nsj = up.ns[jp];
    const float* Lp = &lst[up.off[jp] * 3];
    const float xi = Lp[ri * 3 + 0], yi = Lp[ri * 3 + 1], zi = Lp[ri * 3 + 2];
    float m1 = FLT_MAX, m2 = FLT_MAX;
    for (int m = 0; m < nsj; m++) {
      const float dx = xi - Lp[m * 3 + 0];
      const float dy = yi - Lp[m * 3 + 1];
      const float dz = zi - Lp[m * 3 + 2];
      const float d = dx * dx + dy * dy + dz * dz;
      if (d < m1) { m2 = m1; m1 = d; }
      else if (d < m2) { m2 = d; }
    }
    const float ud = sqrtf(fabsf(m2 + 1e-8f));
    const float dd = ud - up.e[jp];
    const float tt = (dd * dd) / up.eden[jp];
    // weight (p*100)^2 / (5 * NBALLS * ns) folded per percentage:
    const double wj = (jp == 0) ? (0.16   / (5.0 * 1636.0 * 32.0))
                   : (jp == 1) ? (0.64   / (5.0 * 1636.0 * 65.0))
                   : (jp == 2) ? (1.0    / (5.0 * 1636.0 * 81.0))
                   : (jp == 3) ? (1.44   / (5.0 * 1636.0 * 98.0))
                               : (2.56   / (5.0 * 1636.0 * 131.0));
    local += (double)tt * wj;
  }
#pragma unroll
  for (int off = 32; off >= 1; off >>= 1) local += __shfl_down(local, off);
  if (lane == 0) dpart[wv] = local;
  __syncthreads();
  if (tid == 0) {
    uni_part[ball] = dpart[0] + dpart[1] + dpart[2] + dpart[3];
  }
}

// ---------------------------------------------------------------- finalize
// Reference output dtype is float32 (f32 inputs, jnp.stack of f32 scalars)
// -> d_out is float*, NOT bf16. This was the round 0-2 failure.
__global__ __launch_bounds__(256) void fin_kernel(const double* __restrict__ rep_part,
                                                  const double* __restrict__ uni_part,
                                                  float* __restrict__ out) {
  __shared__ double sd[256];
  const int t = threadIdx.x;
  double u = 0.0, r = 0.0;
  for (int i = t; i < NBALLS; i += 256) u += uni_part[i];
  for (int i = t; i < REP_BLOCKS; i += 256) r += rep_part[i];

  sd[t] = u; __syncthreads();
  for (int s = 128; s > 0; s >>= 1) { if (t < s) sd[t] += sd[t + s]; __syncthreads(); }
  const double usum = sd[0];
  __syncthreads();
  sd[t] = r; __syncthreads();
  for (int s = 128; s > 0; s >>= 1) { if (t < s) sd[t] += sd[t + s]; __syncthreads(); }

  if (t == 0) {
    out[0] = (float)usum;                          // uniform loss
    out[1] = (float)(sd[0] * (1.0 / 131072.0));    // repulsion mean over 4*8192*4
  }
}

// ---------------------------------------------------------------- launch
extern "C" void kernel_launch(void* const* d_in, const int* in_sizes, int n_in,
                              void* d_out, int out_size, void* d_ws, size_t ws_size,
                              hipStream_t stream) {
  (void)in_sizes; (void)n_in; (void)out_size; (void)ws_size;
  const float* pcd = (const float*)d_in[0];
  float* out = (float*)d_out;
  int*    fps      = (int*)((char*)d_ws + WS_FPS_OFF);
  double* rep_part = (double*)((char*)d_ws + WS_REP_OFF);
  double* uni_part = (double*)((char*)d_ws + WS_UNI_OFF);

  // f32 array vs python-double scalar comparison: scalar rounds to nearest f32
  const float rep_thr = (float)(0.07 * 0.07);

  UniParams up;
  const double ps[5] = {0.004, 0.008, 0.01, 0.012, 0.016};
  int off = 0;
  for (int j = 0; j < 5; j++) {
    const int ns = (int)(8192.0 * ps[j]);            // 32, 65, 81, 98, 131
    const double r = sqrt(ps[j]);
    up.thr[j] = (float)(r * r);
    const double disk = M_PI * ps[j] / (double)ns;
    const double el = sqrt(2.0 * disk / 1.732);
    up.e[j] = (float)el;
    up.eden[j] = (float)(el + 1e-8);
    up.ns[j] = ns;
    up.off[j] = off;
    off += ns;
  }

  fps_kernel<<<BATCH, 512, 0, stream>>>(pcd, fps);
  rep_kernel<<<REP_BLOCKS, 256, 0, stream>>>(pcd, rep_part, rep_thr);
  uni_kernel<<<NBALLS, 256, 0, stream>>>(pcd, fps, uni_part, up);
  fin_kernel<<<1, 256, 0, stream>>>(rep_part, uni_part, out);
}

// Round 4
// 792.819 us; speedup vs baseline: 1.9698x; 1.9698x over previous
//
#include <hip/hip_runtime.h>
#include <hip/hip_bf16.h>
#include <cmath>
#include <cfloat>

#define BATCH 4
#define NPTS 8192
#define NPOINT 409
#define NBALLS (BATCH * NPOINT)   // 1636
#define REP_NS 20
#define REP_QB 64                 // queries per block
#define REP_SEG 16                // segments per query scan
#define SEG_LEN (NPTS / REP_SEG)  // 512
#define REP_BLOCKS (BATCH * NPTS / REP_QB)  // 512

// ws layout (bytes):
//   [0, 6544)       : fps_idx  int[1636]
//   [8192, 12288)   : rep_part double[512]
//   [12288, 25376)  : uni_part double[1636]
#define WS_FPS_OFF 0
#define WS_REP_OFF 8192
#define WS_UNI_OFF 12288

struct UniParams {
  float  thr[5];
  float  e[5];
  float  eden[5];
  int    ns[5];
  int    off[5];
};

// ---------------------------------------------------------------- FPS
// One block per batch, 1024 threads x 8 points. Exact f32 arithmetic
// (no FMA) to match the reference argmax chain; ties -> smaller index.
__global__ __launch_bounds__(1024) void fps_kernel(const float* __restrict__ pcd,
                                                   int* __restrict__ fps_idx) {
  const int b = blockIdx.x;
  const int t = threadIdx.x;
  const int lane = t & 63, w = t >> 6;
  const float* P = pcd + b * NPTS * 3;

  float px[8], py[8], pz[8], dist[8];
  const int base = t * 8;
#pragma unroll
  for (int k = 0; k < 8; k++) {
    px[k] = P[(base + k) * 3 + 0];
    py[k] = P[(base + k) * 3 + 1];
    pz[k] = P[(base + k) * 3 + 2];
    dist[k] = 1e10f;
  }

  __shared__ float sv[16];
  __shared__ int   si[16];
  __shared__ int   s_far;

  int far = 0;
  for (int s = 0; s < NPOINT; s++) {
    if (t == 0) fps_idx[b * NPOINT + s] = far;
    const float fx = P[far * 3 + 0];
    const float fy = P[far * 3 + 1];
    const float fz = P[far * 3 + 2];

    float best = -1.0f;
    int bidx = 0;
#pragma unroll
    for (int k = 0; k < 8; k++) {
      const float dx = __fsub_rn(px[k], fx);
      const float dy = __fsub_rn(py[k], fy);
      const float dz = __fsub_rn(pz[k], fz);
      const float d = __fadd_rn(__fadd_rn(__fmul_rn(dx, dx), __fmul_rn(dy, dy)),
                                __fmul_rn(dz, dz));
      const float nd = fminf(dist[k], d);
      dist[k] = nd;
      if (nd > best) { best = nd; bidx = base + k; }   // ascending k: first occurrence
    }
#pragma unroll
    for (int off = 32; off >= 1; off >>= 1) {
      const float ov = __shfl_down(best, off);
      const int   oi = __shfl_down(bidx, off);
      if (ov > best) { best = ov; bidx = oi; }
      else if (ov == best && oi < bidx) { bidx = oi; }
    }
    if (lane == 0) { sv[w] = best; si[w] = bidx; }
    __syncthreads();
    if (w == 0) {
      float v  = (lane < 16) ? sv[lane] : -1.0f;
      int   vi = (lane < 16) ? si[lane] : 0x7fffffff;
#pragma unroll
      for (int off = 8; off >= 1; off >>= 1) {
        const float ov = __shfl_down(v, off);
        const int   oi = __shfl_down(vi, off);
        if (ov > v) { v = ov; vi = oi; }
        else if (ov == v && oi < vi) { vi = oi; }
      }
      if (lane == 0) s_far = vi;
    }
    __syncthreads();
    far = s_far;
  }
}

// ---------------------------------------------------------------- repulsion
__device__ __forceinline__ void ins5(float v, float& t0, float& t1, float& t2,
                                     float& t3, float& t4) {
  if (v < t4) {
    t4 = v;
    if (t4 < t3) { float tmp = t3; t3 = t4; t4 = tmp; }
    if (t3 < t2) { float tmp = t2; t2 = t3; t3 = tmp; }
    if (t2 < t1) { float tmp = t1; t1 = t2; t2 = tmp; }
    if (t1 < t0) { float tmp = t0; t0 = t1; t1 = tmp; }
  }
}

__device__ __forceinline__ float rep_term(float d) {
  d = fmaxf(d, 0.0f);
  return 0.07f - sqrtf(d) * expf(-(d / 0.0009f));
}

// Block = 64 queries x 16 segments. lane = query, wave = segment.
// Per-segment: first-20-in-order hit count, first-hit dist, top-5.
// Wave 0 merges segments in index order; exact rescan if cap binds.
__global__ __launch_bounds__(1024) void rep_kernel(const float* __restrict__ pcd,
                                                   double* __restrict__ rep_part,
                                                   float thr) {
  const int tid = threadIdx.x;
  const int lane = tid & 63;
  const int w = tid >> 6;                       // segment index
  const int blk = blockIdx.x;
  const int b = blk >> 7;                       // 128 blocks per batch
  const int q = ((blk & 127) << 6) + lane;
  const float* P = pcd + b * NPTS * 3;

  const float qx = P[q * 3 + 0], qy = P[q * 3 + 1], qz = P[q * 3 + 2];

  int cnt = 0;
  float d0 = 0.0f;
  float t0 = FLT_MAX, t1 = FLT_MAX, t2 = FLT_MAX, t3 = FLT_MAX, t4 = FLT_MAX;

  const float* S = P + w * SEG_LEN * 3;
#pragma unroll 4
  for (int i = 0; i < SEG_LEN; i++) {
    const float x = S[i * 3 + 0];               // wave-uniform address
    const float y = S[i * 3 + 1];
    const float z = S[i * 3 + 2];
    const float dx = qx - x, dy = qy - y, dz = qz - z;
    const float d = dx * dx + dy * dy + dz * dz;
    if (d <= thr && cnt < REP_NS) {
      if (cnt == 0) d0 = d;
      ins5(d, t0, t1, t2, t3, t4);
      cnt++;
    }
  }

  __shared__ float s_t5[REP_SEG][REP_QB][5];
  __shared__ float s_d0[REP_SEG][REP_QB];
  __shared__ int   s_cnt[REP_SEG][REP_QB];
  s_t5[w][lane][0] = t0; s_t5[w][lane][1] = t1; s_t5[w][lane][2] = t2;
  s_t5[w][lane][3] = t3; s_t5[w][lane][4] = t4;
  s_d0[w][lane] = d0;
  s_cnt[w][lane] = cnt;
  __syncthreads();

  if (w == 0) {
    int total = 0;
    float fd0 = 0.0f;
    int first_seen = 0;
    float m0 = FLT_MAX, m1 = FLT_MAX, m2 = FLT_MAX, m3 = FLT_MAX, m4 = FLT_MAX;
#pragma unroll
    for (int s = 0; s < REP_SEG; s++) {
      const int c = s_cnt[s][lane];
      if (c > 0 && !first_seen) { fd0 = s_d0[s][lane]; first_seen = 1; }
      total += c;
#pragma unroll
      for (int j = 0; j < 5; j++) ins5(s_t5[s][lane][j], m0, m1, m2, m3, m4);
    }

    if (total > REP_NS) {
      // cap binds across segments (rare): exact sequential rescan
      int c2 = 0; float dd0 = 0.0f;
      m0 = FLT_MAX; m1 = FLT_MAX; m2 = FLT_MAX; m3 = FLT_MAX; m4 = FLT_MAX;
      for (int i = 0; i < NPTS && c2 < REP_NS; i++) {
        const float dx = qx - P[i * 3 + 0];
        const float dy = qy - P[i * 3 + 1];
        const float dz = qz - P[i * 3 + 2];
        const float d = dx * dx + dy * dy + dz * dz;
        if (d <= thr) {
          if (c2 == 0) dd0 = d;
          ins5(d, m0, m1, m2, m3, m4);
          c2++;
        }
      }
      // c2 == REP_NS here, no padding
    } else {
      for (int c = total; c < REP_NS; c++) ins5(fd0, m0, m1, m2, m3, m4);
    }

    float sum = rep_term(m1) + rep_term(m2) + rep_term(m3) + rep_term(m4);
#pragma unroll
    for (int off = 32; off >= 1; off >>= 1) sum += __shfl_down(sum, off);
    if (lane == 0) rep_part[blk] = (double)sum;
  }
}

// ---------------------------------------------------------------- uniform
__global__ __launch_bounds__(256) void uni_kernel(const float* __restrict__ pcd,
                                                  const int* __restrict__ fps_idx,
                                                  double* __restrict__ uni_part,
                                                  UniParams up) {
  const int ball = blockIdx.x;
  const int b = ball / NPOINT;
  const int tid = threadIdx.x;
  const int lane = tid & 63, wv = tid >> 6;
  const float* P = pcd + b * NPTS * 3;

  const int qidx = fps_idx[ball];
  const float qx = P[qidx * 3 + 0], qy = P[qidx * 3 + 1], qz = P[qidx * 3 + 2];

  __shared__ float lst[407 * 3];
  __shared__ int s_cnt[5];
  __shared__ int wtot[4][5];
  __shared__ double dpart[4];

  if (tid < 5) s_cnt[tid] = 0;
  __syncthreads();

  for (int tile = 0; tile < NPTS; tile += 256) {
    const int j = tile + tid;
    const float x = P[j * 3 + 0];
    const float y = P[j * 3 + 1];
    const float z = P[j * 3 + 2];
    const float dx = qx - x, dy = qy - y, dz = qz - z;
    const float d = dx * dx + dy * dy + dz * dz;

    int hit[5], pre[5];
#pragma unroll
    for (int jp = 0; jp < 5; jp++) {
      const bool h = (d <= up.thr[jp]);
      const unsigned long long m = __ballot(h);
      pre[jp] = __popcll(m & ((1ull << lane) - 1ull));
      if (lane == 0) wtot[wv][jp] = __popcll(m);
      hit[jp] = h ? 1 : 0;
    }
    __syncthreads();
#pragma unroll
    for (int jp = 0; jp < 5; jp++) {
      if (hit[jp]) {
        int woff = 0;
        for (int w2 = 0; w2 < wv; w2++) woff += wtot[w2][jp];
        const int pos = s_cnt[jp] + woff + pre[jp];
        if (pos < up.ns[jp]) {
          float* L = &lst[(up.off[jp] + pos) * 3];
          L[0] = x; L[1] = y; L[2] = z;
        }
      }
    }
    __syncthreads();
    if (tid < 5) {
      s_cnt[tid] += wtot[0][tid] + wtot[1][tid] + wtot[2][tid] + wtot[3][tid];
    }
    __syncthreads();
  }

#pragma unroll
  for (int jp = 0; jp < 5; jp++) {
    const int c = min(s_cnt[jp], up.ns[jp]);
    const float m0x = lst[up.off[jp] * 3 + 0];
    const float m0y = lst[up.off[jp] * 3 + 1];
    const float m0z = lst[up.off[jp] * 3 + 2];
    for (int pos = c + tid; pos < up.ns[jp]; pos += 256) {
      float* L = &lst[(up.off[jp] + pos) * 3];
      L[0] = m0x; L[1] = m0y; L[2] = m0z;
    }
  }
  __syncthreads();

  double local = 0.0;
  for (int r = tid; r < 407; r += 256) {
    const int jp = (r < 32) ? 0 : (r < 97) ? 1 : (r < 178) ? 2 : (r < 276) ? 3 : 4;
    const int ri = r - up.off[jp];
    const int nsj = up.ns[jp];
    const float* Lp = &lst[up.off[jp] * 3];
    const float xi = Lp[ri * 3 + 0], yi = Lp[ri * 3 + 1], zi = Lp[ri * 3 + 2];
    float m1 = FLT_MAX, m2 = FLT_MAX;
    for (int m = 0; m < nsj; m++) {
      const float dx = xi - Lp[m * 3 + 0];
      const float dy = yi - Lp[m * 3 + 1];
      const float dz = zi - Lp[m * 3 + 2];
      const float d = dx * dx + dy * dy + dz * dz;
      if (d < m1) { m2 = m1; m1 = d; }
      else if (d < m2) { m2 = d; }
    }
    const float ud = sqrtf(fabsf(m2 + 1e-8f));
    const float dd = ud - up.e[jp];
    const float tt = (dd * dd) / up.eden[jp];
    const double wj = (jp == 0) ? (0.16 / (5.0 * 1636.0 * 32.0))
                   : (jp == 1) ? (0.64 / (5.0 * 1636.0 * 65.0))
                   : (jp == 2) ? (1.0  / (5.0 * 1636.0 * 81.0))
                   : (jp == 3) ? (1.44 / (5.0 * 1636.0 * 98.0))
                               : (2.56 / (5.0 * 1636.0 * 131.0));
    local += (double)tt * wj;
  }
#pragma unroll
  for (int off = 32; off >= 1; off >>= 1) local += __shfl_down(local, off);
  if (lane == 0) dpart[wv] = local;
  __syncthreads();
  if (tid == 0) {
    uni_part[ball] = dpart[0] + dpart[1] + dpart[2] + dpart[3];
  }
}

// ---------------------------------------------------------------- finalize
__global__ __launch_bounds__(256) void fin_kernel(const double* __restrict__ rep_part,
                                                  const double* __restrict__ uni_part,
                                                  float* __restrict__ out) {
  __shared__ double sd[256];
  const int t = threadIdx.x;
  double u = 0.0, r = 0.0;
  for (int i = t; i < NBALLS; i += 256) u += uni_part[i];
  for (int i = t; i < REP_BLOCKS; i += 256) r += rep_part[i];

  sd[t] = u; __syncthreads();
  for (int s = 128; s > 0; s >>= 1) { if (t < s) sd[t] += sd[t + s]; __syncthreads(); }
  const double usum = sd[0];
  __syncthreads();
  sd[t] = r; __syncthreads();
  for (int s = 128; s > 0; s >>= 1) { if (t < s) sd[t] += sd[t + s]; __syncthreads(); }

  if (t == 0) {
    out[0] = (float)usum;
    out[1] = (float)(sd[0] * (1.0 / 131072.0));
  }
}

// ---------------------------------------------------------------- launch
extern "C" void kernel_launch(void* const* d_in, const int* in_sizes, int n_in,
                              void* d_out, int out_size, void* d_ws, size_t ws_size,
                              hipStream_t stream) {
  (void)in_sizes; (void)n_in; (void)out_size; (void)ws_size;
  const float* pcd = (const float*)d_in[0];
  float* out = (float*)d_out;
  int*    fps      = (int*)((char*)d_ws + WS_FPS_OFF);
  double* rep_part = (double*)((char*)d_ws + WS_REP_OFF);
  double* uni_part = (double*)((char*)d_ws + WS_UNI_OFF);

  const float rep_thr = (float)(0.07 * 0.07);

  UniParams up;
  const double ps[5] = {0.004, 0.008, 0.01, 0.012, 0.016};
  int off = 0;
  for (int j = 0; j < 5; j++) {
    const int ns = (int)(8192.0 * ps[j]);            // 32, 65, 81, 98, 131
    const double r = sqrt(ps[j]);
    up.thr[j] = (float)(r * r);
    const double disk = M_PI * ps[j] / (double)ns;
    const double el = sqrt(2.0 * disk / 1.732);
    up.e[j] = (float)el;
    up.eden[j] = (float)(el + 1e-8);
    up.ns[j] = ns;
    up.off[j] = off;
    off += ns;
  }

  fps_kernel<<<BATCH, 1024, 0, stream>>>(pcd, fps);
  rep_kernel<<<REP_BLOCKS, 1024, 0, stream>>>(pcd, rep_part, rep_thr);
  uni_kernel<<<NBALLS, 256, 0, stream>>>(pcd, fps, uni_part, up);
  fin_kernel<<<1, 256, 0, stream>>>(rep_part, uni_part, out);
}

// Round 5
// 706.915 us; speedup vs baseline: 2.2091x; 1.1215x over previous
//
#include <hip/hip_runtime.h>
#include <hip/hip_bf16.h>
#include <cmath>
#include <cfloat>

#define BATCH 4
#define NPTS 8192
#define NPOINT 409
#define NBALLS (BATCH * NPOINT)   // 1636
#define REP_NS 20
#define REP_QB 64                 // queries per block
#define REP_SEG 4                 // segments per query scan (one per wave)
#define SEG_LEN (NPTS / REP_SEG)  // 2048
#define REP_BLOCKS (BATCH * NPTS / REP_QB)  // 512

// ws layout (bytes):
//   [0, 6544)       : fps_idx  int[1636]
//   [8192, 12288)   : rep_part double[512]
//   [12288, 25376)  : uni_part double[1636]
#define WS_FPS_OFF 0
#define WS_REP_OFF 8192
#define WS_UNI_OFF 12288

struct UniParams {
  float  thr[5];
  float  e[5];
  float  eden[5];
  int    ns[5];
  int    off[5];
};

// ---------------------------------------------------------------- FPS
// One block per batch, 256 threads x 32 points in registers.
// Exact f32 arithmetic (no FMA) to match the reference argmax chain;
// ties -> smaller index. ONE barrier per step: per-wave best goes to a
// parity-indexed LDS slot; every lane redundantly reduces the 4 slots.
__global__ __launch_bounds__(256) void fps_kernel(const float* __restrict__ pcd,
                                                  int* __restrict__ fps_idx) {
  const int b = blockIdx.x;
  const int t = threadIdx.x;
  const int lane = t & 63, w = t >> 6;
  const float* P = pcd + b * NPTS * 3;

  float px[32], py[32], pz[32], dist[32];
  const int base = t * 32;
#pragma unroll
  for (int k = 0; k < 32; k++) {
    px[k] = P[(base + k) * 3 + 0];
    py[k] = P[(base + k) * 3 + 1];
    pz[k] = P[(base + k) * 3 + 2];
    dist[k] = 1e10f;
  }

  __shared__ uint2 s_red[2][4];   // ping-pong: {float bits of best, idx}

  int far = 0;
  for (int s = 0; s < NPOINT; s++) {
    if (t == 0) fps_idx[b * NPOINT + s] = far;
    const float fx = P[far * 3 + 0];
    const float fy = P[far * 3 + 1];
    const float fz = P[far * 3 + 2];

    float best = -1.0f;
    int bidx = 0;
#pragma unroll
    for (int k = 0; k < 32; k++) {
      const float dx = __fsub_rn(px[k], fx);
      const float dy = __fsub_rn(py[k], fy);
      const float dz = __fsub_rn(pz[k], fz);
      const float d = __fadd_rn(__fadd_rn(__fmul_rn(dx, dx), __fmul_rn(dy, dy)),
                                __fmul_rn(dz, dz));
      const float nd = fminf(dist[k], d);
      dist[k] = nd;
      if (nd > best) { best = nd; bidx = base + k; }   // ascending k: first occurrence
    }
    // 64-lane wave reduce; lane order == index order, ties -> smaller index
#pragma unroll
    for (int off = 32; off >= 1; off >>= 1) {
      const float ov = __shfl_down(best, off);
      const int   oi = __shfl_down(bidx, off);
      if (ov > best) { best = ov; bidx = oi; }
      else if (ov == best && oi < bidx) { bidx = oi; }
    }
    const int par = s & 1;
    if (lane == 0) s_red[par][w] = make_uint2(__float_as_uint(best), (unsigned)bidx);
    __syncthreads();
    float v  = __uint_as_float(s_red[par][0].x);
    int   vi = (int)s_red[par][0].y;
#pragma unroll
    for (int w2 = 1; w2 < 4; w2++) {
      const float ov = __uint_as_float(s_red[par][w2].x);
      const int   oi = (int)s_red[par][w2].y;
      if (ov > v) { v = ov; vi = oi; }
      else if (ov == v && oi < vi) { vi = oi; }
    }
    far = vi;   // same in all lanes; no second barrier (ping-pong slots)
  }
}

// ---------------------------------------------------------------- repulsion helpers
__device__ __forceinline__ void ins5(float v, float& t0, float& t1, float& t2,
                                     float& t3, float& t4) {
  if (v < t4) {
    t4 = v;
    if (t4 < t3) { float tmp = t3; t3 = t4; t4 = tmp; }
    if (t3 < t2) { float tmp = t2; t2 = t3; t3 = tmp; }
    if (t2 < t1) { float tmp = t1; t1 = t2; t2 = tmp; }
    if (t1 < t0) { float tmp = t0; t0 = t1; t1 = tmp; }
  }
}

__device__ __forceinline__ float rep_term(float d) {
  d = fmaxf(d, 0.0f);
  return 0.07f - sqrtf(d) * expf(-(d / 0.0009f));
}

// ---------------------------------------------------------------- fused rep+uni
// blocks [0, REP_BLOCKS)           : repulsion, 64 queries x 4 segments
// blocks [REP_BLOCKS, +NBALLS)     : uniform, one ball per block
__global__ __launch_bounds__(256) void repuni_kernel(const float* __restrict__ pcd,
                                                     const int* __restrict__ fps_idx,
                                                     double* __restrict__ rep_part,
                                                     double* __restrict__ uni_part,
                                                     UniParams up, float rep_thr) {
  const int tid = threadIdx.x;
  const int lane = tid & 63;
  const int w = tid >> 6;

  if (blockIdx.x < REP_BLOCKS) {
    // ---------------- repulsion ----------------
    __shared__ float s_t5[REP_SEG][REP_QB][5];
    __shared__ float s_d0[REP_SEG][REP_QB];
    __shared__ int   s_cnt[REP_SEG][REP_QB];

    const int blk = blockIdx.x;
    const int b = blk >> 7;                       // 128 blocks per batch
    const int q = ((blk & 127) << 6) + lane;
    const float* P = pcd + b * NPTS * 3;

    const float qx = P[q * 3 + 0], qy = P[q * 3 + 1], qz = P[q * 3 + 2];

    int cnt = 0;
    float d0 = 0.0f;
    float t0 = FLT_MAX, t1 = FLT_MAX, t2 = FLT_MAX, t3 = FLT_MAX, t4 = FLT_MAX;

    const int wu = __builtin_amdgcn_readfirstlane(w);   // provably wave-uniform
    const float* S = P + wu * SEG_LEN * 3;
#pragma unroll 4
    for (int i = 0; i < SEG_LEN; i++) {
      const float x = S[i * 3 + 0];               // uniform addr -> scalar loads
      const float y = S[i * 3 + 1];
      const float z = S[i * 3 + 2];
      const float dx = qx - x, dy = qy - y, dz = qz - z;
      const float d = dx * dx + dy * dy + dz * dz;
      if (d <= rep_thr && cnt < REP_NS) {
        if (cnt == 0) d0 = d;
        ins5(d, t0, t1, t2, t3, t4);
        cnt++;
      }
    }

    s_t5[w][lane][0] = t0; s_t5[w][lane][1] = t1; s_t5[w][lane][2] = t2;
    s_t5[w][lane][3] = t3; s_t5[w][lane][4] = t4;
    s_d0[w][lane] = d0;
    s_cnt[w][lane] = cnt;
    __syncthreads();

    if (w == 0) {
      int total = 0;
      float fd0 = 0.0f;
      int first_seen = 0;
      float m0 = FLT_MAX, m1 = FLT_MAX, m2 = FLT_MAX, m3 = FLT_MAX, m4 = FLT_MAX;
#pragma unroll
      for (int sg = 0; sg < REP_SEG; sg++) {
        const int c = s_cnt[sg][lane];
        if (c > 0 && !first_seen) { fd0 = s_d0[sg][lane]; first_seen = 1; }
        total += c;
#pragma unroll
        for (int j = 0; j < 5; j++) ins5(s_t5[sg][lane][j], m0, m1, m2, m3, m4);
      }

      if (total > REP_NS) {
        // cap binds across segments (astronomically rare): exact rescan
        int c2 = 0;
        m0 = FLT_MAX; m1 = FLT_MAX; m2 = FLT_MAX; m3 = FLT_MAX; m4 = FLT_MAX;
        for (int i = 0; i < NPTS && c2 < REP_NS; i++) {
          const float dx = qx - P[i * 3 + 0];
          const float dy = qy - P[i * 3 + 1];
          const float dz = qz - P[i * 3 + 2];
          const float d = dx * dx + dy * dy + dz * dz;
          if (d <= rep_thr) { ins5(d, m0, m1, m2, m3, m4); c2++; }
        }
      } else {
        for (int c = total; c < REP_NS; c++) ins5(fd0, m0, m1, m2, m3, m4);
      }

      float sum = rep_term(m1) + rep_term(m2) + rep_term(m3) + rep_term(m4);
#pragma unroll
      for (int off = 32; off >= 1; off >>= 1) sum += __shfl_down(sum, off);
      if (lane == 0) rep_part[blk] = (double)sum;
    }
    return;
  }

  // ---------------- uniform ----------------
  const int ball = blockIdx.x - REP_BLOCKS;
  const int b = ball / NPOINT;
  const float* P = pcd + b * NPTS * 3;

  const int qidx = fps_idx[ball];
  const float qx = P[qidx * 3 + 0], qy = P[qidx * 3 + 1], qz = P[qidx * 3 + 2];

  __shared__ float lst[407 * 3];
  __shared__ int u_cnt[5];
  __shared__ int wtot[4][5];
  __shared__ double dpart[4];

  if (tid < 5) u_cnt[tid] = 0;
  __syncthreads();

  for (int tile = 0; tile < NPTS; tile += 256) {
    const int j = tile + tid;
    const float x = P[j * 3 + 0];
    const float y = P[j * 3 + 1];
    const float z = P[j * 3 + 2];
    const float dx = qx - x, dy = qy - y, dz = qz - z;
    const float d = dx * dx + dy * dy + dz * dz;

    int hit[5], pre[5];
#pragma unroll
    for (int jp = 0; jp < 5; jp++) {
      const bool h = (d <= up.thr[jp]);
      const unsigned long long m = __ballot(h);
      pre[jp] = __popcll(m & ((1ull << lane) - 1ull));
      if (lane == 0) wtot[w][jp] = __popcll(m);
      hit[jp] = h ? 1 : 0;
    }
    __syncthreads();
#pragma unroll
    for (int jp = 0; jp < 5; jp++) {
      if (hit[jp]) {
        int woff = 0;
        for (int w2 = 0; w2 < w; w2++) woff += wtot[w2][jp];
        const int pos = u_cnt[jp] + woff + pre[jp];
        if (pos < up.ns[jp]) {
          float* L = &lst[(up.off[jp] + pos) * 3];
          L[0] = x; L[1] = y; L[2] = z;
        }
      }
    }
    __syncthreads();
    if (tid < 5) {
      u_cnt[tid] += wtot[0][tid] + wtot[1][tid] + wtot[2][tid] + wtot[3][tid];
    }
    __syncthreads();
  }

#pragma unroll
  for (int jp = 0; jp < 5; jp++) {
    const int c = min(u_cnt[jp], up.ns[jp]);
    const float m0x = lst[up.off[jp] * 3 + 0];
    const float m0y = lst[up.off[jp] * 3 + 1];
    const float m0z = lst[up.off[jp] * 3 + 2];
    for (int pos = c + tid; pos < up.ns[jp]; pos += 256) {
      float* L = &lst[(up.off[jp] + pos) * 3];
      L[0] = m0x; L[1] = m0y; L[2] = m0z;
    }
  }
  __syncthreads();

  double local = 0.0;
  for (int r = tid; r < 407; r += 256) {
    const int jp = (r < 32) ? 0 : (r < 97) ? 1 : (r < 178) ? 2 : (r < 276) ? 3 : 4;
    const int ri = r - up.off[jp];
    const int nsj = up.ns[jp];
    const float* Lp = &lst[up.off[jp] * 3];
    const float xi = Lp[ri * 3 + 0], yi = Lp[ri * 3 + 1], zi = Lp[ri * 3 + 2];
    float m1 = FLT_MAX, m2 = FLT_MAX;
    for (int m = 0; m < nsj; m++) {
      const float dx = xi - Lp[m * 3 + 0];
      const float dy = yi - Lp[m * 3 + 1];
      const float dz = zi - Lp[m * 3 + 2];
      const float d = dx * dx + dy * dy + dz * dz;
      if (d < m1) { m2 = m1; m1 = d; }
      else if (d < m2) { m2 = d; }
    }
    const float ud = sqrtf(fabsf(m2 + 1e-8f));
    const float dd = ud - up.e[jp];
    const float tt = (dd * dd) / up.eden[jp];
    const double wj = (jp == 0) ? (0.16 / (5.0 * 1636.0 * 32.0))
                   : (jp == 1) ? (0.64 / (5.0 * 1636.0 * 65.0))
                   : (jp == 2) ? (1.0  / (5.0 * 1636.0 * 81.0))
                   : (jp == 3) ? (1.44 / (5.0 * 1636.0 * 98.0))
                               : (2.56 / (5.0 * 1636.0 * 131.0));
    local += (double)tt * wj;
  }
#pragma unroll
  for (int off = 32; off >= 1; off >>= 1) local += __shfl_down(local, off);
  if (lane == 0) dpart[w] = local;
  __syncthreads();
  if (tid == 0) {
    uni_part[ball] = dpart[0] + dpart[1] + dpart[2] + dpart[3];
  }
}

// ---------------------------------------------------------------- finalize
__global__ __launch_bounds__(256) void fin_kernel(const double* __restrict__ rep_part,
                                                  const double* __restrict__ uni_part,
                                                  float* __restrict__ out) {
  __shared__ double sd[256];
  const int t = threadIdx.x;
  double u = 0.0, r = 0.0;
  for (int i = t; i < NBALLS; i += 256) u += uni_part[i];
  for (int i = t; i < REP_BLOCKS; i += 256) r += rep_part[i];

  sd[t] = u; __syncthreads();
  for (int s = 128; s > 0; s >>= 1) { if (t < s) sd[t] += sd[t + s]; __syncthreads(); }
  const double usum = sd[0];
  __syncthreads();
  sd[t] = r; __syncthreads();
  for (int s = 128; s > 0; s >>= 1) { if (t < s) sd[t] += sd[t + s]; __syncthreads(); }

  if (t == 0) {
    out[0] = (float)usum;
    out[1] = (float)(sd[0] * (1.0 / 131072.0));
  }
}

// ---------------------------------------------------------------- launch
extern "C" void kernel_launch(void* const* d_in, const int* in_sizes, int n_in,
                              void* d_out, int out_size, void* d_ws, size_t ws_size,
                              hipStream_t stream) {
  (void)in_sizes; (void)n_in; (void)out_size; (void)ws_size;
  const float* pcd = (const float*)d_in[0];
  float* out = (float*)d_out;
  int*    fps      = (int*)((char*)d_ws + WS_FPS_OFF);
  double* rep_part = (double*)((char*)d_ws + WS_REP_OFF);
  double* uni_part = (double*)((char*)d_ws + WS_UNI_OFF);

  const float rep_thr = (float)(0.07 * 0.07);

  UniParams up;
  const double ps[5] = {0.004, 0.008, 0.01, 0.012, 0.016};
  int off = 0;
  for (int j = 0; j < 5; j++) {
    const int ns = (int)(8192.0 * ps[j]);            // 32, 65, 81, 98, 131
    const double r = sqrt(ps[j]);
    up.thr[j] = (float)(r * r);
    const double disk = M_PI * ps[j] / (double)ns;
    const double el = sqrt(2.0 * disk / 1.732);
    up.e[j] = (float)el;
    up.eden[j] = (float)(el + 1e-8);
    up.ns[j] = ns;
    up.off[j] = off;
    off += ns;
  }

  fps_kernel<<<BATCH, 256, 0, stream>>>(pcd, fps);
  repuni_kernel<<<REP_BLOCKS + NBALLS, 256, 0, stream>>>(pcd, fps, rep_part,
                                                         uni_part, up, rep_thr);
  fin_kernel<<<1, 256, 0, stream>>>(rep_part, uni_part, out);
}

// Round 6
// 514.724 us; speedup vs baseline: 3.0340x; 1.3734x over previous
//
#include <hip/hip_runtime.h>
#include <hip/hip_bf16.h>
#include <cmath>
#include <cfloat>

#define BATCH 4
#define NPTS 8192
#define NPOINT 409
#define NBALLS (BATCH * NPOINT)   // 1636
#define REP_NS 20
#define REP_QB 64                 // queries per block
#define REP_SEG 4                 // segments per query scan (one per wave)
#define SEG_LEN (NPTS / REP_SEG)  // 2048
#define REP_BLOCKS (BATCH * NPTS / REP_QB)  // 512

// ws layout (bytes):
//   [0, 6544)       : fps_idx  int[1636]
//   [8192, 12288)   : rep_part double[512]
//   [12288, 25376)  : uni_part double[1636]
#define WS_FPS_OFF 0
#define WS_REP_OFF 8192
#define WS_UNI_OFF 12288

struct UniParams {
  float  thr[5];
  float  e[5];
  float  eden[5];
  int    ns[5];
  int    off[5];
};

// u64 max-combine with a DPP-shifted copy (gfx9 rocPRIM wave64 reduce pattern)
template <int CTRL>
__device__ __forceinline__ unsigned long long dpp_max_u64(unsigned long long key) {
  const int lo = __builtin_amdgcn_update_dpp(
      0, (int)(unsigned)(key & 0xFFFFFFFFull), CTRL, 0xf, 0xf, true);
  const int hi = __builtin_amdgcn_update_dpp(
      0, (int)(unsigned)(key >> 32), CTRL, 0xf, 0xf, true);
  const unsigned long long ok =
      ((unsigned long long)(unsigned)hi << 32) | (unsigned)lo;
  return ok > key ? ok : key;
}

// ---------------------------------------------------------------- repulsion helpers
__device__ __forceinline__ void ins5(float v, float& t0, float& t1, float& t2,
                                     float& t3, float& t4) {
  if (v < t4) {
    t4 = v;
    if (t4 < t3) { float tmp = t3; t3 = t4; t4 = tmp; }
    if (t3 < t2) { float tmp = t2; t2 = t3; t3 = tmp; }
    if (t2 < t1) { float tmp = t1; t1 = t2; t2 = tmp; }
    if (t1 < t0) { float tmp = t0; t0 = t1; t1 = tmp; }
  }
}

__device__ __forceinline__ float rep_term(float d) {
  d = fmaxf(d, 0.0f);
  return 0.07f - sqrtf(d) * expf(-(d / 0.0009f));
}

// ---------------------------------------------------------------- fused fps+rep
// blocks [0, BATCH)              : FPS, one block per batch
// blocks [BATCH, +REP_BLOCKS)    : repulsion, 64 queries x 4 segments
__global__ __launch_bounds__(256) void fpsrep_kernel(const float* __restrict__ pcd,
                                                     int* __restrict__ fps_idx,
                                                     double* __restrict__ rep_part,
                                                     float rep_thr) {
  const int tid = threadIdx.x;
  const int lane = tid & 63;
  const int w = tid >> 6;

  if (blockIdx.x < BATCH) {
    // ---------------- FPS ----------------
    // 256 threads x 32 points in registers. Exact f32 (no FMA) to match the
    // reference argmax chain. Argmax via u64 key (dist_bits<<32 | ~idx):
    // max key == max dist, ties -> smaller index, at every reduce level.
    const int b = blockIdx.x;
    const float* P = pcd + b * NPTS * 3;

    float px[32], py[32], pz[32], dist[32];
    const int base = tid * 32;
#pragma unroll
    for (int k = 0; k < 32; k++) {
      px[k] = P[(base + k) * 3 + 0];
      py[k] = P[(base + k) * 3 + 1];
      pz[k] = P[(base + k) * 3 + 2];
      dist[k] = 1e10f;
    }

    __shared__ unsigned long long s_key[2][4];   // ping-pong slots

    int far = 0;
    float fx = P[0], fy = P[1], fz = P[2];
    for (int s = 0; s < NPOINT; s++) {
      if (tid == 0) fps_idx[b * NPOINT + s] = far;

      float best = -1.0f;
      int bidx = 0;
#pragma unroll
      for (int k = 0; k < 32; k++) {
        const float dx = __fsub_rn(px[k], fx);
        const float dy = __fsub_rn(py[k], fy);
        const float dz = __fsub_rn(pz[k], fz);
        const float d = __fadd_rn(__fadd_rn(__fmul_rn(dx, dx), __fmul_rn(dy, dy)),
                                  __fmul_rn(dz, dz));
        const float nd = fminf(dist[k], d);
        dist[k] = nd;
        if (nd > best) { best = nd; bidx = base + k; }  // ascending k: first occurrence
      }
      // best >= 0 always (squared distances), so key ordering == f32 ordering
      unsigned long long key =
          ((unsigned long long)__float_as_uint(best) << 32) |
          (unsigned long long)(0xFFFFFFFFu - (unsigned)bidx);

      // wave64 max-reduce via DPP; result lands in lane 63
      key = dpp_max_u64<0x111>(key);   // row_shr:1
      key = dpp_max_u64<0x112>(key);   // row_shr:2
      key = dpp_max_u64<0x114>(key);   // row_shr:4
      key = dpp_max_u64<0x118>(key);   // row_shr:8
      key = dpp_max_u64<0x142>(key);   // row_bcast:15
      key = dpp_max_u64<0x143>(key);   // row_bcast:31

      const int par = s & 1;
      if (lane == 63) s_key[par][w] = key;
      __syncthreads();
      // every lane redundantly merges the 4 wave winners (no 2nd barrier;
      // ping-pong slot is not rewritten until after the next barrier)
      unsigned long long kb = s_key[par][0];
      const unsigned long long k1 = s_key[par][1];
      const unsigned long long k2 = s_key[par][2];
      const unsigned long long k3 = s_key[par][3];
      if (k1 > kb) kb = k1;
      if (k2 > kb) kb = k2;
      if (k3 > kb) kb = k3;
      far = (int)(0xFFFFFFFFu - (unsigned)(kb & 0xFFFFFFFFull));
      fx = P[far * 3 + 0];
      fy = P[far * 3 + 1];
      fz = P[far * 3 + 2];
    }
    return;
  }

  // ---------------- repulsion ----------------
  __shared__ float s_t5[REP_SEG][REP_QB][5];
  __shared__ float s_d0[REP_SEG][REP_QB];
  __shared__ int   s_cnt[REP_SEG][REP_QB];

  const int blk = blockIdx.x - BATCH;
  const int b = blk >> 7;                       // 128 blocks per batch
  const int q = ((blk & 127) << 6) + lane;
  const float* P = pcd + b * NPTS * 3;

  const float qx = P[q * 3 + 0], qy = P[q * 3 + 1], qz = P[q * 3 + 2];

  int cnt = 0;
  float d0 = 0.0f;
  float t0 = FLT_MAX, t1 = FLT_MAX, t2 = FLT_MAX, t3 = FLT_MAX, t4 = FLT_MAX;

  const int wu = __builtin_amdgcn_readfirstlane(w);
  const float* S = P + wu * SEG_LEN * 3;
#pragma unroll 4
  for (int i = 0; i < SEG_LEN; i++) {
    const float x = S[i * 3 + 0];               // uniform addr -> scalar loads
    const float y = S[i * 3 + 1];
    const float z = S[i * 3 + 2];
    const float dx = qx - x, dy = qy - y, dz = qz - z;
    const float d = dx * dx + dy * dy + dz * dz;
    if (d <= rep_thr && cnt < REP_NS) {
      if (cnt == 0) d0 = d;
      ins5(d, t0, t1, t2, t3, t4);
      cnt++;
    }
  }

  s_t5[w][lane][0] = t0; s_t5[w][lane][1] = t1; s_t5[w][lane][2] = t2;
  s_t5[w][lane][3] = t3; s_t5[w][lane][4] = t4;
  s_d0[w][lane] = d0;
  s_cnt[w][lane] = cnt;
  __syncthreads();

  if (w == 0) {
    int total = 0;
    float fd0 = 0.0f;
    int first_seen = 0;
    float m0 = FLT_MAX, m1 = FLT_MAX, m2 = FLT_MAX, m3 = FLT_MAX, m4 = FLT_MAX;
#pragma unroll
    for (int sg = 0; sg < REP_SEG; sg++) {
      const int c = s_cnt[sg][lane];
      if (c > 0 && !first_seen) { fd0 = s_d0[sg][lane]; first_seen = 1; }
      total += c;
#pragma unroll
      for (int j = 0; j < 5; j++) ins5(s_t5[sg][lane][j], m0, m1, m2, m3, m4);
    }

    if (total > REP_NS) {
      // cap binds across segments (astronomically rare): exact rescan
      int c2 = 0;
      m0 = FLT_MAX; m1 = FLT_MAX; m2 = FLT_MAX; m3 = FLT_MAX; m4 = FLT_MAX;
      for (int i = 0; i < NPTS && c2 < REP_NS; i++) {
        const float dx = qx - P[i * 3 + 0];
        const float dy = qy - P[i * 3 + 1];
        const float dz = qz - P[i * 3 + 2];
        const float d = dx * dx + dy * dy + dz * dz;
        if (d <= rep_thr) { ins5(d, m0, m1, m2, m3, m4); c2++; }
      }
    } else {
      for (int c = total; c < REP_NS; c++) ins5(fd0, m0, m1, m2, m3, m4);
    }

    float sum = rep_term(m1) + rep_term(m2) + rep_term(m3) + rep_term(m4);
#pragma unroll
    for (int off = 32; off >= 1; off >>= 1) sum += __shfl_down(sum, off);
    if (lane == 0) rep_part[blk] = (double)sum;
  }
}

// ---------------------------------------------------------------- uniform
__global__ __launch_bounds__(256) void uni_kernel(const float* __restrict__ pcd,
                                                  const int* __restrict__ fps_idx,
                                                  double* __restrict__ uni_part,
                                                  UniParams up) {
  const int ball = blockIdx.x;
  const int b = ball / NPOINT;
  const int tid = threadIdx.x;
  const int lane = tid & 63, w = tid >> 6;
  const float* P = pcd + b * NPTS * 3;

  const int qidx = fps_idx[ball];
  const float qx = P[qidx * 3 + 0], qy = P[qidx * 3 + 1], qz = P[qidx * 3 + 2];

  __shared__ float lst[407 * 3];
  __shared__ int u_cnt[5];
  __shared__ int wtot[4][5];
  __shared__ double dpart[4];

  if (tid < 5) u_cnt[tid] = 0;
  __syncthreads();

  for (int tile = 0; tile < NPTS; tile += 256) {
    const int j = tile + tid;
    const float x = P[j * 3 + 0];
    const float y = P[j * 3 + 1];
    const float z = P[j * 3 + 2];
    const float dx = qx - x, dy = qy - y, dz = qz - z;
    const float d = dx * dx + dy * dy + dz * dz;

    int hit[5], pre[5];
#pragma unroll
    for (int jp = 0; jp < 5; jp++) {
      const bool h = (d <= up.thr[jp]);
      const unsigned long long m = __ballot(h);
      pre[jp] = __popcll(m & ((1ull << lane) - 1ull));
      if (lane == 0) wtot[w][jp] = __popcll(m);
      hit[jp] = h ? 1 : 0;
    }
    __syncthreads();
#pragma unroll
    for (int jp = 0; jp < 5; jp++) {
      if (hit[jp]) {
        int woff = 0;
        for (int w2 = 0; w2 < w; w2++) woff += wtot[w2][jp];
        const int pos = u_cnt[jp] + woff + pre[jp];
        if (pos < up.ns[jp]) {
          float* L = &lst[(up.off[jp] + pos) * 3];
          L[0] = x; L[1] = y; L[2] = z;
        }
      }
    }
    __syncthreads();
    if (tid < 5) {
      u_cnt[tid] += wtot[0][tid] + wtot[1][tid] + wtot[2][tid] + wtot[3][tid];
    }
    __syncthreads();
  }

#pragma unroll
  for (int jp = 0; jp < 5; jp++) {
    const int c = min(u_cnt[jp], up.ns[jp]);
    const float m0x = lst[up.off[jp] * 3 + 0];
    const float m0y = lst[up.off[jp] * 3 + 1];
    const float m0z = lst[up.off[jp] * 3 + 2];
    for (int pos = c + tid; pos < up.ns[jp]; pos += 256) {
      float* L = &lst[(up.off[jp] + pos) * 3];
      L[0] = m0x; L[1] = m0y; L[2] = m0z;
    }
  }
  __syncthreads();

  double local = 0.0;
  for (int r = tid; r < 407; r += 256) {
    const int jp = (r < 32) ? 0 : (r < 97) ? 1 : (r < 178) ? 2 : (r < 276) ? 3 : 4;
    const int ri = r - up.off[jp];
    const int nsj = up.ns[jp];
    const float* Lp = &lst[up.off[jp] * 3];
    const float xi = Lp[ri * 3 + 0], yi = Lp[ri * 3 + 1], zi = Lp[ri * 3 + 2];
    float m1 = FLT_MAX, m2 = FLT_MAX;
    for (int m = 0; m < nsj; m++) {
      const float dx = xi - Lp[m * 3 + 0];
      const float dy = yi - Lp[m * 3 + 1];
      const float dz = zi - Lp[m * 3 + 2];
      const float d = dx * dx + dy * dy + dz * dz;
      if (d < m1) { m2 = m1; m1 = d; }
      else if (d < m2) { m2 = d; }
    }
    const float ud = sqrtf(fabsf(m2 + 1e-8f));
    const float dd = ud - up.e[jp];
    const float tt = (dd * dd) / up.eden[jp];
    const double wj = (jp == 0) ? (0.16 / (5.0 * 1636.0 * 32.0))
                   : (jp == 1) ? (0.64 / (5.0 * 1636.0 * 65.0))
                   : (jp == 2) ? (1.0  / (5.0 * 1636.0 * 81.0))
                   : (jp == 3) ? (1.44 / (5.0 * 1636.0 * 98.0))
                               : (2.56 / (5.0 * 1636.0 * 131.0));
    local += (double)tt * wj;
  }
#pragma unroll
  for (int off = 32; off >= 1; off >>= 1) local += __shfl_down(local, off);
  if (lane == 0) dpart[w] = local;
  __syncthreads();
  if (tid == 0) {
    uni_part[ball] = dpart[0] + dpart[1] + dpart[2] + dpart[3];
  }
}

// ---------------------------------------------------------------- finalize
__global__ __launch_bounds__(256) void fin_kernel(const double* __restrict__ rep_part,
                                                  const double* __restrict__ uni_part,
                                                  float* __restrict__ out) {
  __shared__ double sd[256];
  const int t = threadIdx.x;
  double u = 0.0, r = 0.0;
  for (int i = t; i < NBALLS; i += 256) u += uni_part[i];
  for (int i = t; i < REP_BLOCKS; i += 256) r += rep_part[i];

  sd[t] = u; __syncthreads();
  for (int s = 128; s > 0; s >>= 1) { if (t < s) sd[t] += sd[t + s]; __syncthreads(); }
  const double usum = sd[0];
  __syncthreads();
  sd[t] = r; __syncthreads();
  for (int s = 128; s > 0; s >>= 1) { if (t < s) sd[t] += sd[t + s]; __syncthreads(); }

  if (t == 0) {
    out[0] = (float)usum;
    out[1] = (float)(sd[0] * (1.0 / 131072.0));
  }
}

// ---------------------------------------------------------------- launch
extern "C" void kernel_launch(void* const* d_in, const int* in_sizes, int n_in,
                              void* d_out, int out_size, void* d_ws, size_t ws_size,
                              hipStream_t stream) {
  (void)in_sizes; (void)n_in; (void)out_size; (void)ws_size;
  const float* pcd = (const float*)d_in[0];
  float* out = (float*)d_out;
  int*    fps      = (int*)((char*)d_ws + WS_FPS_OFF);
  double* rep_part = (double*)((char*)d_ws + WS_REP_OFF);
  double* uni_part = (double*)((char*)d_ws + WS_UNI_OFF);

  const float rep_thr = (float)(0.07 * 0.07);

  UniParams up;
  const double ps[5] = {0.004, 0.008, 0.01, 0.012, 0.016};
  int off = 0;
  for (int j = 0; j < 5; j++) {
    const int ns = (int)(8192.0 * ps[j]);            // 32, 65, 81, 98, 131
    const double r = sqrt(ps[j]);
    up.thr[j] = (float)(r * r);
    const double disk = M_PI * ps[j] / (double)ns;
    const double el = sqrt(2.0 * disk / 1.732);
    up.e[j] = (float)el;
    up.eden[j] = (float)(el + 1e-8);
    up.ns[j] = ns;
    up.off[j] = off;
    off += ns;
  }

  fpsrep_kernel<<<BATCH + REP_BLOCKS, 256, 0, stream>>>(pcd, fps, rep_part, rep_thr);
  uni_kernel<<<NBALLS, 256, 0, stream>>>(pcd, fps, uni_part, up);
  fin_kernel<<<1, 256, 0, stream>>>(rep_part, uni_part, out);
}